// Round 17
// baseline (1476.333 us; speedup 1.0000x reference)
//
#include <hip/hip_runtime.h>
#include <stdint.h>

#define B_ 256
#define T_ 512
#define F_ 128
#define U_ 256
#define H_ 64
#define G4U 1024

typedef __attribute__((ext_vector_type(8))) short short8;
typedef __attribute__((ext_vector_type(4))) float f32x4;
typedef unsigned long long ull;

// LDS-only barrier: NO vmcnt drain.
#define BARRIER_LDS() asm volatile("s_waitcnt lgkmcnt(0)\ns_barrier" ::: "memory")

__device__ __forceinline__ uint16_t f2bf(float f) {
  uint32_t u = __builtin_bit_cast(uint32_t, f);
  u += 0x7fffu + ((u >> 16) & 1u);
  return (uint16_t)(u >> 16);
}
__device__ __forceinline__ float bf2f(uint32_t v) {
  return __builtin_bit_cast(float, (v & 0xffffu) << 16);
}
__device__ __forceinline__ float frcp(float x) {
  float r;
  asm volatile("v_rcp_f32 %0, %1" : "=v"(r) : "v"(x));
  return r;
}
__device__ __forceinline__ float sigm(float z) {
  return frcp(1.0f + __expf(-z));
}
__device__ __forceinline__ ull ald(const ull* p) {
  return __hip_atomic_load(p, __ATOMIC_RELAXED, __HIP_MEMORY_SCOPE_AGENT);
}

// ---------------------------------------------------------------------------
// xz_pre (proven): xz = bias + x_t@kernel, bf16, MFMA C-layout:
//   xz[(bg*L+tt)*16384 + (wd*4+q)*256 + lane*4 + r], wd = member*8 + wave.
// ---------------------------------------------------------------------------
__global__ __launch_bounds__(256, 1) void xz_pre(
    const float* __restrict__ x, const float* __restrict__ kern,
    const float* __restrict__ bias, uint16_t* __restrict__ xz,
    int t0, int L)
{
  const int tid  = threadIdx.x;
  const int lane = tid & 63;
  const int q    = tid >> 6;
  const int il   = lane & 15;
  const int bx   = blockIdx.x;
  const int bg   = bx & 15;
  const int hp   = (bx >> 4) & 1;
  const int tc   = bx >> 5;

  __shared__ __align__(16) uint16_t kern_lds[8192 * 8];     // 128 KB
  __shared__ __align__(16) uint16_t x_stage[2][4][64][8];   // 8 KB dbuf

  for (int s = 0; s < 32; ++s) {
    const int slot = tid + s * 256;
    const int l = slot & 63, kt = (slot >> 6) & 3, ctl = (slot >> 8) & 7, qq = slot >> 11;
    const int col = qq * 256 + (hp * 8 + ctl) * 16 + (l & 15);
    const int kb  = kt * 32 + (l >> 4) * 8;
    short8 v;
    #pragma unroll
    for (int j = 0; j < 8; ++j)
      v[j] = (short)f2bf(kern[(size_t)(kb + j) * G4U + col]);
    *(short8*)&kern_lds[(size_t)slot * 8] = v;
  }
  float bias_r[8];
  #pragma unroll
  for (int ctl = 0; ctl < 8; ++ctl)
    bias_r[ctl] = bias[q * 256 + (hp * 8 + ctl) * 16 + il];

  const int xrow = tid & 15, xfb = (tid >> 4) * 8;
  const int xs_kt = xfb >> 5, xs_l = ((xfb >> 3) & 3) * 16 + xrow;

  float xv[8];
  {
    const float* p = x + ((size_t)(bg * 16 + xrow) * T_ + (t0 + tc * 16)) * F_ + xfb;
    #pragma unroll
    for (int j = 0; j < 8; ++j) xv[j] = p[j];
  }
  __syncthreads();

  for (int tt2 = 0; tt2 < 16; ++tt2) {
    const int t = t0 + tc * 16 + tt2;
    const int bb = tt2 & 1;
    {
      uint16_t* d = &x_stage[bb][xs_kt][xs_l][0];
      #pragma unroll
      for (int j = 0; j < 8; ++j) d[j] = f2bf(xv[j]);
    }
    BARRIER_LDS();
    {
      const int tn = (tt2 < 15) ? t + 1 : t;
      const float* p = x + ((size_t)(bg * 16 + xrow) * T_ + tn) * F_ + xfb;
      #pragma unroll
      for (int j = 0; j < 8; ++j) xv[j] = p[j];
    }
    f32x4 acc[8];
    #pragma unroll
    for (int ctl = 0; ctl < 8; ++ctl)
      acc[ctl] = (f32x4){bias_r[ctl], bias_r[ctl], bias_r[ctl], bias_r[ctl]};
    #pragma unroll
    for (int kt = 0; kt < 4; ++kt) {
      short8 a = *(const short8*)&x_stage[bb][kt][lane][0];
      #pragma unroll
      for (int ctl = 0; ctl < 8; ++ctl) {
        short8 b = *(const short8*)&kern_lds[(size_t)(((q * 8 + ctl) * 4 + kt) * 64 + lane) * 8];
        acc[ctl] = __builtin_amdgcn_mfma_f32_16x16x32_bf16(a, b, acc[ctl], 0, 0, 0);
      }
    }
    uint16_t* ob = xz + (size_t)(bg * L + (t - t0)) * 16384;
    #pragma unroll
    for (int ctl = 0; ctl < 8; ++ctl) {
      const int wd = hp * 8 + ctl;
      const uint32_t lo = (uint32_t)f2bf(acc[ctl][0]) | ((uint32_t)f2bf(acc[ctl][1]) << 16);
      const uint32_t hi = (uint32_t)f2bf(acc[ctl][2]) | ((uint32_t)f2bf(acc[ctl][3]) << 16);
      *(ull*)(ob + (size_t)(wd * 4 + q) * 256 + lane * 4) = (ull)lo | ((ull)hi << 32);
    }
  }
}

// ---------------------------------------------------------------------------
// lstm_pair2: R16's proven pairwise kernel + TWO STAGGERED ROW-CHAINS.
// Chain A = rows {4p,4p+1} (acc j 0,1), chain B = rows {4p+2,4p+3} (j 2,3).
// Independent exchanges per chain; chain B's compute covers chain A's
// visibility window and vice versa (gapA ~0.85P, gapB ~0.75P >= V).
// Per chain: own 16-row h tile with dead rows ZERO (MFMA reads are then
// exact for live rows); 1 ull publish/poll per thread per chain.
// hbuf layout: pub(bgm, chain, parity) = hbuf + ((bgm*2+c)*2+par)*512.
// ---------------------------------------------------------------------------
__global__ __launch_bounds__(512, 2) void lstm_pair2(
    const float* __restrict__ rker, uint16_t* __restrict__ seq,
    ull* __restrict__ hbuf, const uint16_t* __restrict__ xz,
    float* __restrict__ cstbuf, int t0, int L)
{
  const int tid  = threadIdx.x;
  const int lane = tid & 63;
  const int wv   = tid >> 6;
  const int il   = lane & 15;
  const int rg   = lane >> 4;
  const int bg   = blockIdx.x & 15;
  const int m    = blockIdx.x >> 4;
  const int bgm  = bg * 2 + m;
  const int pgm  = bg * 2 + (m ^ 1);

  __shared__ __align__(16) uint16_t hA[2][8][64][8];   // 16 KB (parity)
  __shared__ __align__(16) uint16_t hB[2][8][64][8];   // 16 KB

  // rec B-frags in VGPR/AGPR, own-first static slots (rule #20):
  short8 wf[4][8];
  #pragma unroll
  for (int q = 0; q < 4; ++q) {
    const int gcol = q * U_ + m * 128 + wv * 16 + il;
    #pragma unroll
    for (int kk = 0; kk < 8; ++kk) {
      const int ktg = ((kk & 4) ? (m ^ 1) : m) * 4 + (kk & 3);
      short8 v;
      #pragma unroll
      for (int j = 0; j < 8; ++j)
        v[j] = (short)f2bf(rker[(size_t)(ktg * 32 + rg * 8 + j) * G4U + gcol]);
      wf[q][kk] = v;
    }
  }

  const int u_loc = wv * 16 + il;
  const int Ua  = m * 128 + u_loc;
  const int kta = Ua >> 5, ga = ((Ua & 31) >> 3) * 16, posa = Ua & 7;

  // consume/restore mapping: thread owns member-local unit tid>>2, rowpair tid&3
  const int cu  = tid >> 2;          // 0..127
  const int cp  = (tid & 3) * 4;     // row base
  const int Up  = (m ^ 1) * 128 + cu;
  const int upkt = Up >> 5, upg = ((Up & 31) >> 3) * 16, uppos = Up & 7;
  const int Uo  = m * 128 + cu;      // own-restore unit
  const int uokt = Uo >> 5, uog = ((Uo & 31) >> 3) * 16, uopos = Uo & 7;

  ull* const pubA = hbuf + (size_t)((bgm * 2 + 0) * 2) * 512;   // + parity*512
  ull* const pubB = hbuf + (size_t)((bgm * 2 + 1) * 2) * 512;
  const ull* const peerA = hbuf + (size_t)((pgm * 2 + 0) * 2) * 512;
  const ull* const peerB = hbuf + (size_t)((pgm * 2 + 1) * 2) * 512;

  // zero both h tiles (dead rows MUST be zero for correctness)
  {
    ull* z0 = (ull*)hA;  ull* z1 = (ull*)hB;
    #pragma unroll
    for (int k = 0; k < 4; ++k) { z0[tid + k * 512] = 0; z1[tid + k * 512] = 0; }
  }

  float cA0, cA1, cB0, cB1;
  if (t0 == 0) {
    cA0 = cA1 = cB0 = cB1 = 0.f;
  } else {
    cA0 = cstbuf[(size_t)(bg * 16 + rg * 4 + 0) * U_ + Ua];
    cA1 = cstbuf[(size_t)(bg * 16 + rg * 4 + 1) * U_ + Ua];
    cB0 = cstbuf[(size_t)(bg * 16 + rg * 4 + 2) * U_ + Ua];
    cB1 = cstbuf[(size_t)(bg * 16 + rg * 4 + 3) * U_ + Ua];
  }
  __syncthreads();   // zeroing visible
  if (t0 > 0) {
    // restore OWN rows of h_{t0-1} per chain from our own publishes
    const int rp = (t0 - 1) & 1;
    const ull oA = ald(pubA + (size_t)rp * 512 + tid);
    const ull oB = ald(pubB + (size_t)rp * 512 + tid);
    hA[rp][uokt][uog + cp + 0][uopos] = (uint16_t)oA;
    hA[rp][uokt][uog + cp + 1][uopos] = (uint16_t)(oA >> 16);
    hB[rp][uokt][uog + cp + 2][uopos] = (uint16_t)oB;
    hB[rp][uokt][uog + cp + 3][uopos] = (uint16_t)(oB >> 16);
    __syncthreads();
  }

  // per-wave xz pointer: wd = m*8 + wv
  const uint16_t* const pzbase = xz + (size_t)bg * L * 16384
                               + (size_t)((m * 8 + wv) * 4) * 256 + lane * 4;
  ull zc[4];
  #pragma unroll
  for (int q = 0; q < 4; ++q) zc[q] = *(const ull*)(pzbase + q * 256);

  for (int tt = 0; tt < L; ++tt) {
    const int t  = t0 + tt;
    const int pb = (t - 1) & 1, cb = t & 1;
    // (P) issue both peer polls EARLY
    const ull* ppA = peerA + (size_t)pb * 512 + tid;
    const ull* ppB = peerB + (size_t)pb * 512 + tid;
    ull pvA = 0, pvB = 0;
    if (t > 0) {
      pvA = ald(ppA); pvB = ald(ppB);
      __builtin_amdgcn_sched_barrier(0);
    }
    // (Z) acc init from xz (both chains share the unpack values)
    f32x4 accA[4], accB[4];
    #pragma unroll
    for (int q = 0; q < 4; ++q) {
      const uint32_t lo = (uint32_t)zc[q];
      const uint32_t hi = (uint32_t)(zc[q] >> 32);
      f32x4 z;
      z[0] = bf2f(lo); z[1] = bf2f(lo >> 16);
      z[2] = bf2f(hi); z[3] = bf2f(hi >> 16);
      accA[q] = z; accB[q] = z;
    }
    {
      const int ntt = (tt + 1 < L) ? tt + 1 : tt;
      const uint16_t* pn = pzbase + (size_t)ntt * 16384;
      #pragma unroll
      for (int q = 0; q < 4; ++q) zc[q] = *(const ull*)(pn + q * 256);
    }
    if (t > 0) {
      // (OA)(OB) own-half MFMA for both chains (covers poll latency)
      #pragma unroll
      for (int kk = 0; kk < 4; ++kk) {
        short8 aA = *(const short8*)&hA[pb][m * 4 + kk][lane][0];
        #pragma unroll
        for (int q = 0; q < 4; ++q)
          accA[q] = __builtin_amdgcn_mfma_f32_16x16x32_bf16(aA, wf[q][kk], accA[q], 0, 0, 0);
      }
      #pragma unroll
      for (int kk = 0; kk < 4; ++kk) {
        short8 aB = *(const short8*)&hB[pb][m * 4 + kk][lane][0];
        #pragma unroll
        for (int q = 0; q < 4; ++q)
          accB[q] = __builtin_amdgcn_mfma_f32_16x16x32_bf16(aB, wf[q][kk], accB[q], 0, 0, 0);
      }
      // (WA) wait chain A + unpack peer rows {cp, cp+1}
      const uint32_t expt = (uint32_t)t;
      while ((uint32_t)(pvA >> 32) != expt) pvA = ald(ppA);
      hA[pb][upkt][upg + cp + 0][uppos] = (uint16_t)pvA;
      hA[pb][upkt][upg + cp + 1][uppos] = (uint16_t)(pvA >> 16);
    }
    BARRIER_LDS();   // (BAR1) peer-A rows visible
    if (t > 0) {
      #pragma unroll
      for (int kk = 0; kk < 4; ++kk) {
        short8 aA = *(const short8*)&hA[pb][(m ^ 1) * 4 + kk][lane][0];
        #pragma unroll
        for (int q = 0; q < 4; ++q)
          accA[q] = __builtin_amdgcn_mfma_f32_16x16x32_bf16(aA, wf[q][4 + kk], accA[q], 0, 0, 0);
      }
    }
    // (GA) gates chain A (j = 0,1) + publish + own-h + seq
    {
      const float zi0 = accA[0][0], zf0 = accA[1][0], zg0 = accA[2][0], zo0 = accA[3][0];
      const float zi1 = accA[0][1], zf1 = accA[1][1], zg1 = accA[2][1], zo1 = accA[3][1];
      const float i0 = sigm(zi0), f0 = sigm(zf0), g0 = zg0 * sigm(zg0), o0 = sigm(zo0);
      const float i1 = sigm(zi1), f1 = sigm(zf1), g1 = zg1 * sigm(zg1), o1 = sigm(zo1);
      cA0 = f0 * cA0 + i0 * g0;
      cA1 = f1 * cA1 + i1 * g1;
      const uint16_t b0 = f2bf(o0 * (cA0 * sigm(cA0)));
      const uint16_t b1 = f2bf(o1 * (cA1 * sigm(cA1)));
      __hip_atomic_store(pubA + (size_t)cb * 512 + u_loc * 4 + rg,
                         (ull)((uint32_t)b0 | ((uint32_t)b1 << 16))
                           | ((ull)(uint32_t)(t + 1) << 32),
                         __ATOMIC_RELAXED, __HIP_MEMORY_SCOPE_AGENT);
      hA[cb][kta][ga + rg * 4 + 0][posa] = b0;
      hA[cb][kta][ga + rg * 4 + 1][posa] = b1;
      seq[((size_t)(bg * 16 + rg * 4 + 0) * T_ + t) * U_ + Ua] = b0;
      seq[((size_t)(bg * 16 + rg * 4 + 1) * T_ + t) * U_ + Ua] = b1;
    }
    if (t > 0) {
      // (WB) wait chain B + unpack peer rows {cp+2, cp+3}
      const uint32_t expt = (uint32_t)t;
      while ((uint32_t)(pvB >> 32) != expt) pvB = ald(ppB);
      hB[pb][upkt][upg + cp + 2][uppos] = (uint16_t)pvB;
      hB[pb][upkt][upg + cp + 3][uppos] = (uint16_t)(pvB >> 16);
    }
    BARRIER_LDS();   // (BAR2) peer-B rows visible; hA[cb] writes ordered
    if (t > 0) {
      #pragma unroll
      for (int kk = 0; kk < 4; ++kk) {
        short8 aB = *(const short8*)&hB[pb][(m ^ 1) * 4 + kk][lane][0];
        #pragma unroll
        for (int q = 0; q < 4; ++q)
          accB[q] = __builtin_amdgcn_mfma_f32_16x16x32_bf16(aB, wf[q][4 + kk], accB[q], 0, 0, 0);
      }
    }
    // (GB) gates chain B (j = 2,3) + publish + own-h + seq
    {
      const float zi0 = accB[0][2], zf0 = accB[1][2], zg0 = accB[2][2], zo0 = accB[3][2];
      const float zi1 = accB[0][3], zf1 = accB[1][3], zg1 = accB[2][3], zo1 = accB[3][3];
      const float i0 = sigm(zi0), f0 = sigm(zf0), g0 = zg0 * sigm(zg0), o0 = sigm(zo0);
      const float i1 = sigm(zi1), f1 = sigm(zf1), g1 = zg1 * sigm(zg1), o1 = sigm(zo1);
      cB0 = f0 * cB0 + i0 * g0;
      cB1 = f1 * cB1 + i1 * g1;
      const uint16_t b0 = f2bf(o0 * (cB0 * sigm(cB0)));
      const uint16_t b1 = f2bf(o1 * (cB1 * sigm(cB1)));
      __hip_atomic_store(pubB + (size_t)cb * 512 + u_loc * 4 + rg,
                         (ull)((uint32_t)b0 | ((uint32_t)b1 << 16))
                           | ((ull)(uint32_t)(t + 1) << 32),
                         __ATOMIC_RELAXED, __HIP_MEMORY_SCOPE_AGENT);
      hB[cb][kta][ga + rg * 4 + 2][posa] = b0;
      hB[cb][kta][ga + rg * 4 + 3][posa] = b1;
      seq[((size_t)(bg * 16 + rg * 4 + 2) * T_ + t) * U_ + Ua] = b0;
      seq[((size_t)(bg * 16 + rg * 4 + 3) * T_ + t) * U_ + Ua] = b1;
    }
    BARRIER_LDS();   // (BAR3) hA/hB[cb] visible for next iteration's own-MFMA
  }
  // phase epilogue: checkpoint cst (h persists in hbuf publishes)
  cstbuf[(size_t)(bg * 16 + rg * 4 + 0) * U_ + Ua] = cA0;
  cstbuf[(size_t)(bg * 16 + rg * 4 + 1) * U_ + Ua] = cA1;
  cstbuf[(size_t)(bg * 16 + rg * 4 + 2) * U_ + Ua] = cB0;
  cstbuf[(size_t)(bg * 16 + rg * 4 + 3) * U_ + Ua] = cB1;
}

// ---------------------------------------------------------------------------
// Fallback (ws too small): R8's verified pairwise kernel (full T, fused x).
// ---------------------------------------------------------------------------
__global__ __launch_bounds__(512, 2) void lstm_fallback(
    const float* __restrict__ x, const float* __restrict__ kern,
    const float* __restrict__ rker, const float* __restrict__ bias,
    uint16_t* __restrict__ seq, ull* __restrict__ hbuf)
{
  const int tid  = threadIdx.x;
  const int lane = tid & 63;
  const int wv   = tid >> 6;
  const int il   = lane & 15;
  const int rg   = lane >> 4;
  const int bg   = blockIdx.x & 15;
  const int m    = blockIdx.x >> 4;

  __shared__ __align__(16) uint16_t x_stage[4][64][8];
  __shared__ __align__(16) uint16_t h_stage[2][8][64][8];
  __shared__ __align__(16) uint16_t kern_lds[8192 * 8];

  short8 wf[4][8];
  float  bias_r[4];
  #pragma unroll
  for (int q = 0; q < 4; ++q) {
    const int gcol = q * U_ + m * 128 + wv * 16 + il;
    bias_r[q] = bias[gcol];
    #pragma unroll
    for (int kk = 0; kk < 8; ++kk) {
      const int ktg = ((kk & 4) ? (m ^ 1) : m) * 4 + (kk & 3);
      short8 v;
      #pragma unroll
      for (int j = 0; j < 8; ++j)
        v[j] = (short)f2bf(rker[(size_t)(ktg * 32 + rg * 8 + j) * G4U + gcol]);
      wf[q][kk] = v;
    }
  }
  for (int s = 0; s < 16; ++s) {
    const int slot = tid + s * 512;
    const int ln = slot & 63, kt = (slot >> 6) & 3, ct = slot >> 8;
    const int col = (ct >> 3) * U_ + m * 128 + (ct & 7) * 16 + (ln & 15);
    const int kb  = kt * 32 + (ln >> 4) * 8;
    short8 v;
    #pragma unroll
    for (int j = 0; j < 8; ++j)
      v[j] = (short)f2bf(kern[(size_t)(kb + j) * G4U + col]);
    *(short8*)&kern_lds[(size_t)slot * 8] = v;
  }
  const int xkt = tid >> 7;
  const int xln = (tid >> 1) & 63;
  const int xj0 = (tid & 1) * 4;
  const int xrow = xln & 15;
  const int xk0  = xkt * 32 + (xln >> 4) * 8 + xj0;
  const int Ua  = m * 128 + wv * 16 + il;
  const int kta = Ua >> 5, ga = ((Ua & 31) >> 3) * 16, posa = Ua & 7;
  ull* const pub_s = hbuf + (size_t)(bg * 2 + m) * 2048;
  const ull* const pub_p = hbuf + (size_t)(bg * 2 + (m ^ 1)) * 2048;
  float cst[4];
  #pragma unroll
  for (int j = 0; j < 4; ++j) cst[j] = 0.f;
  float xp[4];
  {
    const float* p = x + ((size_t)(bg * 16 + xrow) * T_ + 0) * F_ + xk0;
    #pragma unroll
    for (int j = 0; j < 4; ++j) xp[j] = p[j];
    uint16_t* d = (uint16_t*)x_stage + tid * 4;
    #pragma unroll
    for (int j = 0; j < 4; ++j) d[j] = f2bf(xp[j]);
  }
  __syncthreads();
  for (int t = 0; t < T_; ++t) {
    const ull* pp = pub_p + (size_t)((t - 1) & 1) * 1024 + tid * 2;
    ull pv0 = 0, pv1 = 0;
    if (t > 0) {
      pv0 = ald(pp); pv1 = ald(pp + 1);
      __builtin_amdgcn_sched_barrier(0);
    }
    {
      const int tn = (t + 1 < T_) ? t + 1 : t;
      const float* p = x + ((size_t)(bg * 16 + xrow) * T_ + tn) * F_ + xk0;
      #pragma unroll
      for (int j = 0; j < 4; ++j) xp[j] = p[j];
    }
    f32x4 acc[4];
    #pragma unroll
    for (int q = 0; q < 4; ++q)
      acc[q] = (f32x4){bias_r[q], bias_r[q], bias_r[q], bias_r[q]};
    #pragma unroll
    for (int kt = 0; kt < 4; ++kt) {
      short8 a = *(const short8*)&x_stage[kt][lane][0];
      #pragma unroll
      for (int q = 0; q < 4; ++q) {
        short8 b = *(const short8*)&kern_lds[(size_t)(((q * 8 + wv) * 4 + kt) * 64 + lane) * 8];
        acc[q] = __builtin_amdgcn_mfma_f32_16x16x32_bf16(a, b, acc[q], 0, 0, 0);
      }
    }
    if (t > 0) {
      const int p_ = (t - 1) & 1;
      #pragma unroll
      for (int kk = 0; kk < 4; ++kk) {
        short8 a = *(const short8*)&h_stage[p_][m * 4 + kk][lane][0];
        #pragma unroll
        for (int q = 0; q < 4; ++q)
          acc[q] = __builtin_amdgcn_mfma_f32_16x16x32_bf16(a, wf[q][kk], acc[q], 0, 0, 0);
      }
      const uint32_t expt = (uint32_t)t;
      while (((uint32_t)(pv0 >> 32) != expt) | ((uint32_t)(pv1 >> 32) != expt)) {
        pv0 = ald(pp); pv1 = ald(pp + 1);
      }
      const int u_loc2 = tid >> 2;
      const int U  = (m ^ 1) * 128 + u_loc2;
      const int kt = U >> 5, g = ((U & 31) >> 3) * 16, pos = U & 7;
      const int rb = (tid & 3) * 4;
      h_stage[p_][kt][g + rb + 0][pos] = (uint16_t)pv0;
      h_stage[p_][kt][g + rb + 1][pos] = (uint16_t)(pv0 >> 16);
      h_stage[p_][kt][g + rb + 2][pos] = (uint16_t)pv1;
      h_stage[p_][kt][g + rb + 3][pos] = (uint16_t)(pv1 >> 16);
    }
    BARRIER_LDS();
    if (t > 0) {
      const int p_ = (t - 1) & 1;
      #pragma unroll
      for (int kk = 0; kk < 4; ++kk) {
        short8 a = *(const short8*)&h_stage[p_][(m ^ 1) * 4 + kk][lane][0];
        #pragma unroll
        for (int q = 0; q < 4; ++q)
          acc[q] = __builtin_amdgcn_mfma_f32_16x16x32_bf16(a, wf[q][4 + kk], acc[q], 0, 0, 0);
      }
    }
    {
      uint16_t* d = (uint16_t*)x_stage + tid * 4;
      #pragma unroll
      for (int j = 0; j < 4; ++j) d[j] = f2bf(xp[j]);
    }
    {
      uint16_t b16[4];
      #pragma unroll
      for (int j = 0; j < 4; ++j) {
        const float zi = acc[0][j], zf = acc[1][j];
        const float zg = acc[2][j], zo = acc[3][j];
        const float ii = sigm(zi), ff = sigm(zf);
        const float gg = zg * sigm(zg), oo = sigm(zo);
        const float c  = ff * cst[j] + ii * gg;
        cst[j] = c;
        b16[j] = f2bf(oo * (c * sigm(c)));
      }
      const int s2 = t & 1;
      ull* pw = pub_s + (size_t)s2 * 1024 + (size_t)(wv * 16 + il) * 8 + rg * 2;
      const ull tg = (ull)(uint32_t)(t + 1) << 32;
      __hip_atomic_store(pw,     (ull)((uint32_t)b16[0] | ((uint32_t)b16[1] << 16)) | tg,
                         __ATOMIC_RELAXED, __HIP_MEMORY_SCOPE_AGENT);
      __hip_atomic_store(pw + 1, (ull)((uint32_t)b16[2] | ((uint32_t)b16[3] << 16)) | tg,
                         __ATOMIC_RELAXED, __HIP_MEMORY_SCOPE_AGENT);
      #pragma unroll
      for (int j = 0; j < 4; ++j) {
        h_stage[s2][kta][ga + rg * 4 + j][posa] = b16[j];
        seq[((size_t)(bg * 16 + rg * 4 + j) * T_ + t) * U_ + Ua] = b16[j];
      }
    }
    BARRIER_LDS();
  }
}

// ---------------------------------------------------------------------------
// Head GEMM + reduce (unchanged, verified).
// ---------------------------------------------------------------------------
__global__ __launch_bounds__(256, 1) void head_kernel(
    const uint16_t* __restrict__ seq, const float* __restrict__ w_out,
    float* __restrict__ partials)
{
  const int g    = blockIdx.x;
  const int tid  = threadIdx.x;
  const int lane = tid & 63;
  const int wv   = tid >> 6;

  f32x4 acc[4][4];
  #pragma unroll
  for (int i = 0; i < 4; ++i)
    #pragma unroll
    for (int c = 0; c < 4; ++c) acc[i][c] = (f32x4){0.f, 0.f, 0.f, 0.f};

  for (int ks = 0; ks < 64; ++ks) {
    const int krow = g * 2048 + ks * 32 + (lane >> 4) * 8;
    short8 bf[4];
    #pragma unroll
    for (int c = 0; c < 4; ++c) {
      short8 v;
      #pragma unroll
      for (int j = 0; j < 8; ++j)
        v[j] = (short)f2bf(w_out[(size_t)(krow + j) * H_ + c * 16 + (lane & 15)]);
      bf[c] = v;
    }
    #pragma unroll
    for (int i = 0; i < 4; ++i) {
      const int b = (wv * 4 + i) * 16 + (lane & 15);
      short8 a = *(const short8*)(seq + (size_t)b * (T_ * U_) + krow);
      #pragma unroll
      for (int c = 0; c < 4; ++c)
        acc[i][c] = __builtin_amdgcn_mfma_f32_16x16x32_bf16(a, bf[c], acc[i][c], 0, 0, 0);
    }
  }
  #pragma unroll
  for (int i = 0; i < 4; ++i)
    #pragma unroll
    for (int c = 0; c < 4; ++c)
      #pragma unroll
      for (int r = 0; r < 4; ++r) {
        const int b = wv * 64 + i * 16 + (lane >> 4) * 4 + r;
        partials[((size_t)g * B_ + b) * H_ + c * 16 + (lane & 15)] = acc[i][c][r];
      }
}

__global__ void reduce_kernel(const float* __restrict__ partials,
                              const float* __restrict__ b_out,
                              float* __restrict__ out)
{
  const int i = blockIdx.x * 256 + threadIdx.x;
  float s = b_out[i & (H_ - 1)];
  #pragma unroll 8
  for (int g = 0; g < 64; ++g) s += partials[(size_t)g * (B_ * H_) + i];
  out[i] = s;
}

// ---------------------------------------------------------------------------
extern "C" void kernel_launch(void* const* d_in, const int* in_sizes, int n_in,
                              void* d_out, int out_size, void* d_ws, size_t ws_size,
                              hipStream_t stream) {
  (void)in_sizes; (void)n_in; (void)out_size;
  const float* x     = (const float*)d_in[0];
  const float* kern  = (const float*)d_in[1];
  const float* rker  = (const float*)d_in[2];
  const float* bias  = (const float*)d_in[3];
  const float* w_out = (const float*)d_in[4];
  const float* b_out = (const float*)d_in[5];
  float* out = (float*)d_out;

  char* ws = (char*)d_ws;
  const size_t seq_bytes  = (size_t)B_ * T_ * U_ * 2;    // 64 MB
  const size_t hbuf_bytes = (size_t)32 * 2048 * 8;       // 512 KB (tags)
  const size_t part_bytes = (size_t)64 * B_ * H_ * 4;    // 4 MB
  const size_t cst_bytes  = (size_t)B_ * U_ * 4;         // 256 KB
  uint16_t* seq      = (uint16_t*)ws;
  ull*      hbuf     = (ull*)(ws + seq_bytes);
  float*    partials = (float*)(ws + seq_bytes + hbuf_bytes);
  float*    cstbuf   = (float*)(ws + seq_bytes + hbuf_bytes + part_bytes);
  const size_t xz_off = seq_bytes + hbuf_bytes + part_bytes + cst_bytes;
  uint16_t* xzbuf = (uint16_t*)(ws + xz_off);

  // largest phase length whose bf16 xz tile fits: xz(L) = L/2 MB
  int L = 0;
  const int cand[4] = {128, 64, 32, 16};
  for (int i = 0; i < 4; ++i) {
    if (ws_size >= xz_off + (size_t)cand[i] * 524288) { L = cand[i]; break; }
  }

  // tag re-init each launch (tags cycle 1..512 across graph replays)
  hipMemsetAsync(hbuf, 0, hbuf_bytes, stream);

  if (L > 0) {
    for (int t0 = 0; t0 < T_; t0 += L) {
      xz_pre<<<2 * L, 256, 0, stream>>>(x, kern, bias, xzbuf, t0, L);
      lstm_pair2<<<32, 512, 0, stream>>>(rker, seq, hbuf, xzbuf, cstbuf, t0, L);
    }
  } else {
    lstm_fallback<<<32, 512, 0, stream>>>(x, kern, rker, bias, seq, hbuf);
  }
  head_kernel<<<64, 256, 0, stream>>>(seq, w_out, partials);
  reduce_kernel<<<64, 256, 0, stream>>>(partials, b_out, out);
}